// Round 2
// baseline (499.073 us; speedup 1.0000x reference)
//
#include <hip/hip_runtime.h>

#define DIM 4096
#define BM 128
#define BN 128
#define BK 32

typedef _Float16 half8 __attribute__((ext_vector_type(8)));
typedef _Float16 half4v __attribute__((ext_vector_type(4)));
typedef float floatx4 __attribute__((ext_vector_type(4)));

// Async global->LDS, 16B per lane. LDS dest is wave-uniform base + lane*16.
__device__ __forceinline__ void async_copy16(const _Float16* g, _Float16* l) {
    __builtin_amdgcn_global_load_lds(
        (const __attribute__((address_space(1))) void*)g,
        (__attribute__((address_space(3))) void*)l,
        16, 0, 0);
}

// C[i,j] = sum_k A[i,k] * B[j,k]   ("bt" layout: both operands row-major along K)
// LDS tiles are XOR-swizzled at 16B-chunk granularity to kill bank conflicts:
//   chunk stored at slot p of row r is  c = p ^ ((r>>1)&3)
// Staging threads fetch the permuted global chunk; readers invert the swizzle.
// Since wm and i*16 are ≡0 (mod 4) after >>1, the reader swizzle is a per-lane
// constant (no inner-loop VALU cost).
template <bool QUANT>
__global__ void gemm_bt(const _Float16* __restrict__ A,
                        const _Float16* __restrict__ B,
                        const float* __restrict__ cb,
                        _Float16* __restrict__ Yq,
                        float* __restrict__ C)
{
    __shared__ _Float16 As[BM * BK];
    __shared__ _Float16 Bs[BN * BK];
    __shared__ float    s_bnd[15];
    __shared__ _Float16 s_cb[16];

    const int t    = threadIdx.x;       // 256 threads = 4 waves
    const int lane = t & 63;
    const int wid  = t >> 6;
    const int wm   = (wid >> 1) * 64;   // wave tile origin within 128x128 block tile
    const int wn   = (wid & 1) * 64;
    const int bm   = blockIdx.x * BM;
    const int bn   = blockIdx.y * BN;

    if (QUANT) {
        if (t < 16) s_cb[t]  = (_Float16)cb[t];
        if (t < 15) s_bnd[t] = 0.5f * (cb[t] + cb[t + 1]);
    }

    // staging: thread t owns LDS position (row sr, 16B-slot p); it must fetch
    // the swizzled global chunk ck.
    const int sr = t >> 2;
    const int p  = t & 3;
    const int ck = (p ^ ((sr >> 1) & 3)) * 8;
    const _Float16* ga = A + (size_t)(bm + sr) * DIM + ck;
    const _Float16* gb = B + (size_t)(bn + sr) * DIM + ck;
    _Float16* lA = As + t * 8;
    _Float16* lB = Bs + t * 8;

    // MFMA fragment addressing (16x16x32 f16):
    // A[m=lane&15][k=(lane>>4)*8 + j]; swizzle-corrected LDS slot.
    const int frow = lane & 15;
    const int kg   = lane >> 4;                 // k-chunk 0..3
    const int slot = kg ^ ((frow >> 1) & 3);    // swizzle inverse
    const int roff = frow * BK + slot * 8;

    floatx4 acc[4][4] = {};

    for (int k0 = 0; k0 < DIM; k0 += BK) {
        async_copy16(ga + k0,            lA);
        async_copy16(ga + k0 + 64 * DIM, lA + 64 * BK);
        async_copy16(gb + k0,            lB);
        async_copy16(gb + k0 + 64 * DIM, lB + 64 * BK);
        __syncthreads();

        half8 aF[4], bF[4];
#pragma unroll
        for (int i = 0; i < 4; ++i) {
            aF[i] = *(const half8*)&As[(wm + i * 16) * BK + roff];
            bF[i] = *(const half8*)&Bs[(wn + i * 16) * BK + roff];
        }
#pragma unroll
        for (int i = 0; i < 4; ++i)
#pragma unroll
            for (int j = 0; j < 4; ++j)
                acc[i][j] = __builtin_amdgcn_mfma_f32_16x16x32_f16(aF[i], bF[j], acc[i][j], 0, 0, 0);
        __syncthreads();
    }

    // D layout: col = lane&15, row = (lane>>4)*4 + reg  [m89-verified]
    if (QUANT) {
        float bnd[15];
#pragma unroll
        for (int b = 0; b < 15; ++b) bnd[b] = s_bnd[b];
#pragma unroll
        for (int i = 0; i < 4; ++i) {
            const int gr0 = bm + wm + i * 16 + (lane >> 4) * 4;
#pragma unroll
            for (int j = 0; j < 4; ++j) {
                const int gc = bn + wn + j * 16 + (lane & 15);
#pragma unroll
                for (int rr = 0; rr < 4; ++rr) {
                    const float v = acc[i][j][rr];
                    int idx = 0;
#pragma unroll
                    for (int b = 0; b < 15; ++b) idx += (v > bnd[b]) ? 1 : 0;
                    Yq[(size_t)(gr0 + rr) * DIM + gc] = s_cb[idx];
                }
            }
        }
    } else {
#pragma unroll
        for (int i = 0; i < 4; ++i) {
            const int gr0 = bm + wm + i * 16 + (lane >> 4) * 4;
#pragma unroll
            for (int j = 0; j < 4; ++j) {
                const int gc = bn + wn + j * 16 + (lane & 15);
#pragma unroll
                for (int rr = 0; rr < 4; ++rr)
                    C[(size_t)(gr0 + rr) * DIM + gc] = acc[i][j][rr];
            }
        }
    }
}

// x (fp32) -> f16, 4 elements/thread
__global__ void convert_f16(const float* __restrict__ in, _Float16* __restrict__ out)
{
    const size_t i = ((size_t)blockIdx.x * 256 + threadIdx.x) * 4;
    const float4 v = *(const float4*)(in + i);
    half4v h;
    h.x = (_Float16)v.x; h.y = (_Float16)v.y; h.z = (_Float16)v.z; h.w = (_Float16)v.w;
    *(half4v*)(out + i) = h;
}

// Pi (fp32) -> Pi_f16 (straight) and PiT_f16 (transposed).
// 64x64 tile per block, 256 threads. float4 loads, half4 stores both ways.
// LDS tile stored TRANSPOSED (tile[col][row]) so the PiT write phase reads
// contiguous half4s. Row stride 68 halves = 136 B (mult of 8 -> aligned half4,
// conflict-free vector reads; scalar writes are 4-way which is cheap).
__global__ void prep_pi(const float* __restrict__ Pi,
                        _Float16* __restrict__ Pif,
                        _Float16* __restrict__ PiT)
{
    __shared__ _Float16 tile[64][68];
    const int t  = threadIdx.x;
    const int r0 = t >> 4;          // 0..15
    const int c4 = (t & 15) * 4;    // 0..60
    const int y0 = blockIdx.y * 64; // global row origin
    const int x0 = blockIdx.x * 64; // global col origin
#pragma unroll
    for (int ii = 0; ii < 4; ++ii) {
        const int r = ii * 16 + r0;
        const float4 v = *(const float4*)(Pi + (size_t)(y0 + r) * DIM + x0 + c4);
        half4v h;
        h.x = (_Float16)v.x; h.y = (_Float16)v.y; h.z = (_Float16)v.z; h.w = (_Float16)v.w;
        *(half4v*)(Pif + (size_t)(y0 + r) * DIM + x0 + c4) = h;
        tile[c4 + 0][r] = h.x;
        tile[c4 + 1][r] = h.y;
        tile[c4 + 2][r] = h.z;
        tile[c4 + 3][r] = h.w;
    }
    __syncthreads();
#pragma unroll
    for (int ii = 0; ii < 4; ++ii) {
        const int c = ii * 16 + r0;   // tile column = PiT row offset
        *(half4v*)(PiT + (size_t)(x0 + c) * DIM + y0 + c4) = *(const half4v*)&tile[c][c4];
    }
}

extern "C" void kernel_launch(void* const* d_in, const int* in_sizes, int n_in,
                              void* d_out, int out_size, void* d_ws, size_t ws_size,
                              hipStream_t stream)
{
    (void)in_sizes; (void)n_in; (void)out_size; (void)ws_size;
    const float* x  = (const float*)d_in[0];
    const float* Pi = (const float*)d_in[1];
    const float* cb = (const float*)d_in[2];
    float* out = (float*)d_out;

    char* ws = (char*)d_ws;
    const size_t MB32 = (size_t)DIM * DIM * sizeof(_Float16);  // 32 MiB
    _Float16* xh  = (_Float16*)(ws);
    _Float16* pih = (_Float16*)(ws + MB32);
    _Float16* pit = (_Float16*)(ws + 2 * MB32);
    _Float16* yh  = (_Float16*)(ws + 3 * MB32);

    convert_f16<<<dim3(DIM * DIM / (256 * 4)), dim3(256), 0, stream>>>(x, xh);
    prep_pi<<<dim3(DIM / 64, DIM / 64), dim3(256), 0, stream>>>(Pi, pih, pit);

    // GEMM1: y = x @ Pi^T, fused Lloyd-Max quantize -> y_tilde (f16)
    gemm_bt<true><<<dim3(DIM / BM, DIM / BN), dim3(256), 0, stream>>>(xh, pih, cb, yh, nullptr);
    // GEMM2: x_tilde = y_tilde @ Pi  ==  "bt" GEMM against PiT
    gemm_bt<false><<<dim3(DIM / BM, DIM / BN), dim3(256), 0, stream>>>(yh, pit, cb, nullptr, out);
}

// Round 3
// 434.536 us; speedup vs baseline: 1.1485x; 1.1485x over previous
//
#include <hip/hip_runtime.h>

#define DIM 4096
#define BM 128
#define BN 128
#define BK 64

typedef _Float16 half8 __attribute__((ext_vector_type(8)));
typedef _Float16 half4v __attribute__((ext_vector_type(4)));
typedef float floatx4 __attribute__((ext_vector_type(4)));

// Async global->LDS, 16B per lane. LDS dest is wave-uniform base + lane*16.
__device__ __forceinline__ void async_copy16(const _Float16* g, _Float16* l) {
    __builtin_amdgcn_global_load_lds(
        (const __attribute__((address_space(1))) void*)g,
        (__attribute__((address_space(3))) void*)l,
        16, 0, 0);
}

// C[i,j] = sum_k A[i,k] * B[j,k]   ("bt" layout: both operands row-major along K)
// BK=64: 32 MFMAs between barrier pairs (vs 16 at BK=32) to amortize the
// compiler's vmcnt(0)-before-s_barrier drain. LDS row = 64 halves = 128 B =
// exactly 32 banks, so 16B chunks are XOR-swizzled: slot = chunk ^ (row&7).
// Staging threads fetch the permuted global chunk; readers invert the swizzle
// (per-lane constant offsets, one per k-step).
template <bool QUANT>
__global__ void gemm_bt(const _Float16* __restrict__ A,
                        const _Float16* __restrict__ B,
                        const float* __restrict__ cb,
                        _Float16* __restrict__ Yq,
                        float* __restrict__ C)
{
    __shared__ _Float16 As[BM * BK];   // 16 KiB
    __shared__ _Float16 Bs[BN * BK];   // 16 KiB
    __shared__ float    s_bnd[15];
    __shared__ _Float16 s_cb[16];

    const int t    = threadIdx.x;       // 256 threads = 4 waves
    const int lane = t & 63;
    const int wid  = t >> 6;
    const int wm   = (wid >> 1) * 64;   // wave tile origin within 128x128 block tile
    const int wn   = (wid & 1) * 64;
    const int bm   = blockIdx.x * BM;
    const int bn   = blockIdx.y * BN;

    if (QUANT) {
        if (t < 16) s_cb[t]  = (_Float16)cb[t];
        if (t < 15) s_bnd[t] = 0.5f * (cb[t] + cb[t + 1]);
    }

    // staging: thread t owns LDS (row sr = t>>3, 16B-slot p = t&7) within each
    // 32-row call-group; fetches swizzled global chunk ck.
    const int sr = t >> 3;              // 0..31
    const int p  = t & 7;
    const int ck = (p ^ (sr & 7)) * 8;  // global k-offset (halves)
    const _Float16* ga = A + (size_t)(bm + sr) * DIM + ck;
    const _Float16* gb = B + (size_t)(bn + sr) * DIM + ck;
    _Float16* lA = As + t * 8;          // linear thread order (global_load_lds req.)
    _Float16* lB = Bs + t * 8;

    // MFMA fragment addressing (16x16x32 f16): A[m=lane&15][k=(lane>>4)*8 + j].
    // Swizzle inverse: chunk c = ks*4 + kg lives at slot c ^ (frow&7).
    const int frow = lane & 15;
    const int kg   = lane >> 4;                       // k-chunk within 32-slice
    const int off0 = frow * BK + ((kg + 0) ^ (frow & 7)) * 8;   // ks=0
    const int off1 = frow * BK + ((kg + 4) ^ (frow & 7)) * 8;   // ks=1 (kg+4 < 8, XOR-safe)

    floatx4 acc[4][4] = {};

    for (int k0 = 0; k0 < DIM; k0 += BK) {
#pragma unroll
        for (int j = 0; j < 4; ++j) {
            async_copy16(ga + k0 + 32 * j * DIM, lA + 32 * j * BK);
            async_copy16(gb + k0 + 32 * j * DIM, lB + 32 * j * BK);
        }
        __syncthreads();

#pragma unroll
        for (int ks = 0; ks < 2; ++ks) {
            const int ro = (ks == 0) ? off0 : off1;
            half8 aF[4], bF[4];
#pragma unroll
            for (int i = 0; i < 4; ++i) {
                aF[i] = *(const half8*)&As[(wm + i * 16) * BK + ro];
                bF[i] = *(const half8*)&Bs[(wn + i * 16) * BK + ro];
            }
#pragma unroll
            for (int i = 0; i < 4; ++i)
#pragma unroll
                for (int j = 0; j < 4; ++j)
                    acc[i][j] = __builtin_amdgcn_mfma_f32_16x16x32_f16(aF[i], bF[j], acc[i][j], 0, 0, 0);
        }
        __syncthreads();
    }

    // D layout: col = lane&15, row = (lane>>4)*4 + reg  [m89-verified]
    if (QUANT) {
        float bnd[15];
#pragma unroll
        for (int b = 0; b < 15; ++b) bnd[b] = s_bnd[b];
#pragma unroll
        for (int i = 0; i < 4; ++i) {
            const int gr0 = bm + wm + i * 16 + (lane >> 4) * 4;
#pragma unroll
            for (int j = 0; j < 4; ++j) {
                const int gc = bn + wn + j * 16 + (lane & 15);
#pragma unroll
                for (int rr = 0; rr < 4; ++rr) {
                    const float v = acc[i][j][rr];
                    int idx = 0;
#pragma unroll
                    for (int b = 0; b < 15; ++b) idx += (v > bnd[b]) ? 1 : 0;
                    Yq[(size_t)(gr0 + rr) * DIM + gc] = s_cb[idx];
                }
            }
        }
    } else {
#pragma unroll
        for (int i = 0; i < 4; ++i) {
            const int gr0 = bm + wm + i * 16 + (lane >> 4) * 4;
#pragma unroll
            for (int j = 0; j < 4; ++j) {
                const int gc = bn + wn + j * 16 + (lane & 15);
#pragma unroll
                for (int rr = 0; rr < 4; ++rr)
                    C[(size_t)(gr0 + rr) * DIM + gc] = acc[i][j][rr];
            }
        }
    }
}

// x (fp32) -> f16, 4 elements/thread
__global__ void convert_f16(const float* __restrict__ in, _Float16* __restrict__ out)
{
    const size_t i = ((size_t)blockIdx.x * 256 + threadIdx.x) * 4;
    const float4 v = *(const float4*)(in + i);
    half4v h;
    h.x = (_Float16)v.x; h.y = (_Float16)v.y; h.z = (_Float16)v.z; h.w = (_Float16)v.w;
    *(half4v*)(out + i) = h;
}

// Pi (fp32) -> Pi_f16 (straight) and PiT_f16 (transposed).
// 64x64 tile per block, 256 threads. float4 loads, half4 stores both ways.
// LDS tile stored TRANSPOSED (tile[col][row]); stride 68 halves gives 4-way
// conflicts on the scalar writes (cheap) and conflict-free half4 reads.
__global__ void prep_pi(const float* __restrict__ Pi,
                        _Float16* __restrict__ Pif,
                        _Float16* __restrict__ PiT)
{
    __shared__ _Float16 tile[64][68];
    const int t  = threadIdx.x;
    const int r0 = t >> 4;          // 0..15
    const int c4 = (t & 15) * 4;    // 0..60
    const int y0 = blockIdx.y * 64; // global row origin
    const int x0 = blockIdx.x * 64; // global col origin
#pragma unroll
    for (int ii = 0; ii < 4; ++ii) {
        const int r = ii * 16 + r0;
        const float4 v = *(const float4*)(Pi + (size_t)(y0 + r) * DIM + x0 + c4);
        half4v h;
        h.x = (_Float16)v.x; h.y = (_Float16)v.y; h.z = (_Float16)v.z; h.w = (_Float16)v.w;
        *(half4v*)(Pif + (size_t)(y0 + r) * DIM + x0 + c4) = h;
        tile[c4 + 0][r] = h.x;
        tile[c4 + 1][r] = h.y;
        tile[c4 + 2][r] = h.z;
        tile[c4 + 3][r] = h.w;
    }
    __syncthreads();
#pragma unroll
    for (int ii = 0; ii < 4; ++ii) {
        const int c = ii * 16 + r0;   // tile column = PiT row offset
        *(half4v*)(PiT + (size_t)(x0 + c) * DIM + y0 + c4) = *(const half4v*)&tile[c][c4];
    }
}

extern "C" void kernel_launch(void* const* d_in, const int* in_sizes, int n_in,
                              void* d_out, int out_size, void* d_ws, size_t ws_size,
                              hipStream_t stream)
{
    (void)in_sizes; (void)n_in; (void)out_size; (void)ws_size;
    const float* x  = (const float*)d_in[0];
    const float* Pi = (const float*)d_in[1];
    const float* cb = (const float*)d_in[2];
    float* out = (float*)d_out;

    char* ws = (char*)d_ws;
    const size_t MB32 = (size_t)DIM * DIM * sizeof(_Float16);  // 32 MiB
    _Float16* xh  = (_Float16*)(ws);
    _Float16* pih = (_Float16*)(ws + MB32);
    _Float16* pit = (_Float16*)(ws + 2 * MB32);
    _Float16* yh  = (_Float16*)(ws + 3 * MB32);

    convert_f16<<<dim3(DIM * DIM / (256 * 4)), dim3(256), 0, stream>>>(x, xh);
    prep_pi<<<dim3(DIM / 64, DIM / 64), dim3(256), 0, stream>>>(Pi, pih, pit);

    // GEMM1: y = x @ Pi^T, fused Lloyd-Max quantize -> y_tilde (f16)
    gemm_bt<true><<<dim3(DIM / BM, DIM / BN), dim3(256), 0, stream>>>(xh, pih, cb, yh, nullptr);
    // GEMM2: x_tilde = y_tilde @ Pi  ==  "bt" GEMM against PiT
    gemm_bt<false><<<dim3(DIM / BM, DIM / BN), dim3(256), 0, stream>>>(yh, pit, cb, nullptr, out);
}